// Round 4
// baseline (97.652 us; speedup 1.0000x reference)
//
#include <hip/hip_runtime.h>
#include <hip/hip_bf16.h>
#include <cstdint>

#define Cc 64
#define Hh 128
#define Ww 128
#define OCn 128
#define HBLK 4
#define WT 64
#define WLs 72
#define NT 18
#define SLOT_SHORTS (WLs * Cc)  // 4608 shorts = 9216 B per row slot

typedef float f32x4 __attribute__((ext_vector_type(4)));
typedef __bf16 bf16x8 __attribute__((ext_vector_type(8)));
typedef short s16x8 __attribute__((ext_vector_type(8)));

union bs8 { s16x8 s; bf16x8 b; };
__device__ __forceinline__ bf16x8 as_bf16x8(s16x8 s) { bs8 u; u.s = s; return u.b; }

// ---------------- weight pack: (CK,OC) fp32 -> bf16 A-fragments ----------------
// wp[(t*8 + mb)*64 + lane], k-step order t = ((kh*3+kw)*2 + chalf)
__global__ void pack_w_kernel(const float* __restrict__ w, s16x8* __restrict__ wp) {
  int idx = blockIdx.x * 256 + threadIdx.x;
  if (idx >= NT * 8 * 64) return;
  int l = idx & 63;
  int mb = (idx >> 6) & 7;
  int t = idx >> 9;
  int ch = t & 1;
  int o = t >> 1;
  int kh = o / 3, kw = o % 3;
  int oc = mb * 16 + (l & 15);
  int kl0 = (l >> 4) * 8;
  bf16x8 v;
#pragma unroll
  for (int j = 0; j < 8; ++j) {
    int c = ch * 32 + kl0 + j;
    int ko = (c * 3 + kh) * 3 + kw;
    v[j] = (__bf16)w[ko * OCn + oc];
  }
  bs8 u; u.b = v;
  wp[idx] = u.s;
}

// ---------------- fused conv: fp32 NCHW in, transpose-in-staging, MFMA ----------------
__global__ __launch_bounds__(256) void conv_mfma_kernel(
    const float* __restrict__ x, const s16x8* __restrict__ wpf,
    float* __restrict__ out) {
  __shared__ __align__(16) short xt[4 * SLOT_SHORTS];
  int tid = threadIdx.x;
  int bid = blockIdx.x;
  int wt = bid & 1;
  int hb = (bid >> 1) & 31;
  int b = bid >> 6;
  int h0 = hb * HBLK;
  int wv = tid >> 6, lane = tid & 63;
  int l15 = lane & 15, l4 = lane >> 4;
  int ws = wt * WT - 4;  // aligned 72-pixel load window start

  // Each lane owns channel c = lane; per pass p, pixel-group g = wv + 4p
  // (4 fp32 pixels). LDS index wl = pixel - (wt*64 - 1) in [0,66).
  auto stage_load = [&](int h_img, f32x4* r) {
    bool hok = (h_img >= 0) && (h_img < Hh);
    const float* base = x + (((size_t)(b * Cc + lane)) * Hh + (hok ? h_img : 0)) * Ww;
#pragma unroll
    for (int p = 0; p < 5; ++p) {
      int g = wv + 4 * p;
      int p0 = ws + g * 4;
      bool ok = hok && (g < 18) && (p0 >= 0) && (p0 < Ww);
      r[p] = ok ? *(const f32x4*)(base + p0) : (f32x4){0.f, 0.f, 0.f, 0.f};
    }
  };
  auto stage_write = [&](int h_img, const f32x4* r) {
    int slot = (h_img + 1) & 3;
    short* sb = &xt[slot * SLOT_SHORTS];
#pragma unroll
    for (int p = 0; p < 5; ++p) {
      int g = wv + 4 * p;
      if (g >= 18) continue;  // wave-uniform
#pragma unroll
      for (int j = 0; j < 4; ++j) {
        int wl = g * 4 + j - 3;
        if (wl < 0 || wl >= 66) continue;  // wave-uniform
        __bf16 v = (__bf16)r[p][j];
        sb[wl * Cc + (lane ^ ((wl & 7) << 3))] = *(short*)&v;
      }
    }
  };

  // prologue: stage rows h0-1, h0, h0+1
  {
    f32x4 r0[5], r1[5], r2[5];
    stage_load(h0 - 1, r0);
    stage_load(h0, r1);
    stage_load(h0 + 1, r2);
    stage_write(h0 - 1, r0);
    stage_write(h0, r1);
    stage_write(h0 + 1, r2);
  }

  f32x4 pre[5];
  for (int i = 0; i < HBLK; ++i) {
    int h = h0 + i;
    __syncthreads();  // staged rows visible; prior readers done
    if (i < HBLK - 1) stage_load(h + 2, pre);  // issue loads early (T14)

    f32x4 acc[2][4];
#pragma unroll
    for (int mi = 0; mi < 2; ++mi)
#pragma unroll
      for (int ni = 0; ni < 4; ++ni)
        acc[mi][ni] = (f32x4){0.f, 0.f, 0.f, 0.f};

#pragma unroll
    for (int t = 0; t < NT; ++t) {
      int kh = t / 6, kw = (t >> 1) % 3, ch = t & 1;
      bf16x8 a0 = as_bf16x8(wpf[(t * 8 + wv * 2 + 0) * 64 + lane]);
      bf16x8 a1 = as_bf16x8(wpf[(t * 8 + wv * 2 + 1) * 64 + lane]);
      int slot = (h + kh) & 3;
      int cgr = ch * 4 + l4;  // reader's channel-chunk index
#pragma unroll
      for (int ni = 0; ni < 4; ++ni) {
        int wl2 = ni * 16 + l15 + kw;
        int caddr = slot * SLOT_SHORTS + wl2 * Cc + ((cgr ^ (wl2 & 7)) << 3);
        bf16x8 bfr = as_bf16x8(*(const s16x8*)&xt[caddr]);
        acc[0][ni] = __builtin_amdgcn_mfma_f32_16x16x32_bf16(a0, bfr, acc[0][ni], 0, 0, 0);
        acc[1][ni] = __builtin_amdgcn_mfma_f32_16x16x32_bf16(a1, bfr, acc[1][ni], 0, 0, 0);
      }
    }

    // D mapping: col(px)=lane&15, row(oc)=(lane>>4)*4 + r
#pragma unroll
    for (int mi = 0; mi < 2; ++mi)
#pragma unroll
      for (int ni = 0; ni < 4; ++ni) {
        int oc = wv * 32 + mi * 16 + l4 * 4;
        int w_img = wt * WT + ni * 16 + l15;
        float* po = out + (((size_t)(b * OCn + oc)) * Hh + h) * Ww + w_img;
#pragma unroll
        for (int r = 0; r < 4; ++r)
          __builtin_nontemporal_store(acc[mi][ni][r], po + (size_t)r * Hh * Ww);
      }

    if (i < HBLK - 1) stage_write(h + 2, pre);  // write late, after compute
  }
}

extern "C" void kernel_launch(void* const* d_in, const int* in_sizes, int n_in,
                              void* d_out, int out_size, void* d_ws, size_t ws_size,
                              hipStream_t stream) {
  const float* x = (const float*)d_in[0];
  const float* w = (const float*)d_in[1];
  float* out = (float*)d_out;
  s16x8* wpf = (s16x8*)d_ws;
  pack_w_kernel<<<36, 256, 0, stream>>>(w, wpf);
  conv_mfma_kernel<<<1024, 256, 0, stream>>>(x, (const s16x8*)wpf, out);
}

// Round 5
// 71.465 us; speedup vs baseline: 1.3664x; 1.3664x over previous
//
#include <hip/hip_runtime.h>
#include <hip/hip_bf16.h>
#include <cstdint>

#define Cc 64
#define Hh 128
#define Ww 128
#define OCn 128
#define HBLK 8
#define WT 64
#define WLs 72
#define NT 18
#define SLOT_SHORTS (WLs * Cc)  // 4608 shorts = 9216 B per row slot

typedef float f32x4 __attribute__((ext_vector_type(4)));
typedef __bf16 bf16x8 __attribute__((ext_vector_type(8)));
typedef short s16x8 __attribute__((ext_vector_type(8)));

union bs8 { s16x8 s; bf16x8 b; };
__device__ __forceinline__ bf16x8 as_bf16x8(s16x8 s) { bs8 u; u.s = s; return u.b; }

// ---------------- weight pack: (CK,OC) fp32 -> bf16 A-fragments ----------------
// wp[(t*8 + mb)*64 + lane], k-step order t = ((kh*3+kw)*2 + chalf)
__global__ void pack_w_kernel(const float* __restrict__ w, s16x8* __restrict__ wp) {
  int idx = blockIdx.x * 256 + threadIdx.x;
  if (idx >= NT * 8 * 64) return;
  int l = idx & 63;
  int mb = (idx >> 6) & 7;
  int t = idx >> 9;
  int ch = t & 1;
  int o = t >> 1;
  int kh = o / 3, kw = o % 3;
  int oc = mb * 16 + (l & 15);
  int kl0 = (l >> 4) * 8;
  bf16x8 v;
#pragma unroll
  for (int j = 0; j < 8; ++j) {
    int c = ch * 32 + kl0 + j;
    int ko = (c * 3 + kh) * 3 + kw;
    v[j] = (__bf16)w[ko * OCn + oc];
  }
  bs8 u; u.b = v;
  wp[idx] = u.s;
}

// ---------------- fused conv: coalesced fp32 loads, LDS transpose, MFMA ----------------
// LDS slot layout: 72 px (wl = px - wt*64 + 4) x 64 ch, channel-chunk XOR-swizzled.
__global__ __launch_bounds__(256, 2) void conv_mfma_kernel(
    const float* __restrict__ x, const s16x8* __restrict__ wpf,
    float* __restrict__ out) {
  __shared__ __align__(16) short xt[4 * SLOT_SHORTS];
  int tid = threadIdx.x;
  int bid = blockIdx.x;
  int wt = bid & 1;
  int hb = (bid >> 1) & 15;
  int b = bid >> 5;
  int h0 = hb * HBLK;
  int wv = tid >> 6, lane = tid & 63;
  int l15 = lane & 15, l4 = lane >> 4;

  // Preload ALL A-fragments (weights) into registers once; reused every row.
  bf16x8 af[NT][2];
#pragma unroll
  for (int t = 0; t < NT; ++t)
#pragma unroll
    for (int mi = 0; mi < 2; ++mi)
      af[t][mi] = as_bf16x8(wpf[(t * 8 + wv * 2 + mi) * 64 + lane]);

  // Per-thread staging tasks: i = tid + p*256 (p=4 only for tid<128);
  // c = i/18 (channel), g = i%18 (pixel-group of 4). Coalesced: consecutive
  // lanes -> consecutive 16B of the same channel row.
  int tc[5], tg[5], tw0[5];
  bool tvalid[5];
#pragma unroll
  for (int p = 0; p < 5; ++p) {
    int i = tid + p * 256;
    int c = i / 18, g = i - c * 18;
    tc[p] = c;
    tg[p] = g;
    tw0[p] = wt * WT - 4 + g * 4;
    tvalid[p] = (p < 4 || tid < 128) && !(wt == 0 && g == 0) && !(wt == 1 && g == 17);
  }

  auto stage_load = [&](int h_img, f32x4* r) {
    bool hok = (unsigned)h_img < (unsigned)Hh;
#pragma unroll
    for (int p = 0; p < 5; ++p) {
      bool ok = hok && tvalid[p];
      const float* src = x + (((size_t)(b * Cc + tc[p]) * Hh) + h_img) * Ww + tw0[p];
      r[p] = ok ? *(const f32x4*)src : (f32x4){0.f, 0.f, 0.f, 0.f};
    }
  };
  auto stage_write = [&](int h_img, const f32x4* r) {
    int slot = (h_img + 1) & 3;
    short* sb = &xt[slot * SLOT_SHORTS];
#pragma unroll
    for (int p = 0; p < 5; ++p) {
      if (p == 4 && tid >= 128) continue;
#pragma unroll
      for (int j = 0; j < 4; ++j) {
        int wl = tg[p] * 4 + j;
        __bf16 v = (__bf16)r[p][j];
        sb[wl * Cc + (tc[p] ^ ((wl & 7) << 3))] = *(short*)&v;
      }
    }
  };

  // prologue: stage rows h0-1, h0, h0+1 (loads all issued before writes)
  {
    f32x4 r0[5], r1[5], r2[5];
    stage_load(h0 - 1, r0);
    stage_load(h0, r1);
    stage_load(h0 + 1, r2);
    stage_write(h0 - 1, r0);
    stage_write(h0, r1);
    stage_write(h0 + 1, r2);
  }

  f32x4 pre[5];
  for (int i = 0; i < HBLK; ++i) {
    int h = h0 + i;
    __syncthreads();  // slots h..h+2 ready; all waves in same iteration
    if (i < HBLK - 1) stage_load(h + 2, pre);  // issue loads early (T14)

    f32x4 acc[2][4];
#pragma unroll
    for (int mi = 0; mi < 2; ++mi)
#pragma unroll
      for (int ni = 0; ni < 4; ++ni)
        acc[mi][ni] = (f32x4){0.f, 0.f, 0.f, 0.f};

#pragma unroll
    for (int t = 0; t < NT; ++t) {
      int kh = t / 6, kw = (t >> 1) % 3, ch = t & 1;
      int slot = (h + kh) & 3;
      int cgr = ch * 4 + l4;  // reader's channel-chunk index
#pragma unroll
      for (int ni = 0; ni < 4; ++ni) {
        int wl2 = ni * 16 + l15 + kw + 3;
        int caddr = slot * SLOT_SHORTS + wl2 * Cc + ((cgr ^ (wl2 & 7)) << 3);
        bf16x8 bfr = as_bf16x8(*(const s16x8*)&xt[caddr]);
        acc[0][ni] = __builtin_amdgcn_mfma_f32_16x16x32_bf16(af[t][0], bfr, acc[0][ni], 0, 0, 0);
        acc[1][ni] = __builtin_amdgcn_mfma_f32_16x16x32_bf16(af[t][1], bfr, acc[1][ni], 0, 0, 0);
      }
    }

    // D mapping: col(px)=lane&15, row(oc)=(lane>>4)*4 + r
#pragma unroll
    for (int mi = 0; mi < 2; ++mi)
#pragma unroll
      for (int ni = 0; ni < 4; ++ni) {
        int oc = wv * 32 + mi * 16 + l4 * 4;
        int w_img = wt * WT + ni * 16 + l15;
        float* po = out + (((size_t)(b * OCn + oc)) * Hh + h) * Ww + w_img;
#pragma unroll
        for (int r = 0; r < 4; ++r)
          __builtin_nontemporal_store(acc[mi][ni][r], po + (size_t)r * Hh * Ww);
      }

    if (i < HBLK - 1) stage_write(h + 2, pre);  // write late, after compute
  }
}

extern "C" void kernel_launch(void* const* d_in, const int* in_sizes, int n_in,
                              void* d_out, int out_size, void* d_ws, size_t ws_size,
                              hipStream_t stream) {
  const float* x = (const float*)d_in[0];
  const float* w = (const float*)d_in[1];
  float* out = (float*)d_out;
  s16x8* wpf = (s16x8*)d_ws;
  pack_w_kernel<<<36, 256, 0, stream>>>(w, wpf);
  conv_mfma_kernel<<<512, 256, 0, stream>>>(x, (const s16x8*)wpf, out);
}

// Round 6
// 62.281 us; speedup vs baseline: 1.5679x; 1.1475x over previous
//
#include <hip/hip_runtime.h>
#include <hip/hip_bf16.h>
#include <cstdint>

#define Cc 64
#define Hh 128
#define Ww 128
#define OCn 128
#define HBLK 4
#define WT 64
#define WLs 72
#define HP 130
#define WP 136
#define NT 18
#define SLOT_SHORTS (WLs * Cc)  // 4608 shorts = 9216 B per row slot
#define XP_BYTES (((size_t)16 * HP * WP * Cc) * 2)  // 36,208,640
#define PRE_BLOCKS (16 * HP)                        // 2080, divisible by 8

typedef float f32x4 __attribute__((ext_vector_type(4)));
typedef __bf16 bf16x8 __attribute__((ext_vector_type(8)));
typedef short s16x8 __attribute__((ext_vector_type(8)));

union bs8 { s16x8 s; bf16x8 b; };
__device__ __forceinline__ bf16x8 as_bf16x8(s16x8 s) { bs8 u; u.s = s; return u.b; }

// ---------------- fused pre-pass + weight pack ----------------
// xp[b][hp][wp][c], hp = h+1 in [0,130), wp = w+1 in [0,136); zeros at borders.
// XCD-aligned: work u = (bid>>3) + (bid&7)*260  ->  XCD k owns b in {2k, 2k+1}.
// Blocks [PRE_BLOCKS, PRE_BLOCKS+36) pack the ternary weight into A-fragments:
// wpf[(t*8 + mb)*64 + lane], k-step order t = ((kh*3+kw)*2 + chalf).
__global__ __launch_bounds__(256) void prepass_kernel(const float* __restrict__ x,
                                                      const float* __restrict__ w,
                                                      unsigned short* __restrict__ xp,
                                                      s16x8* __restrict__ wpf) {
  int bid = blockIdx.x;
  int t = threadIdx.x;
  if (bid >= PRE_BLOCKS) {
    int idx = (bid - PRE_BLOCKS) * 256 + t;  // < 9216
    int l = idx & 63;
    int mb = (idx >> 6) & 7;
    int tt = idx >> 9;
    int ch = tt & 1;
    int o = tt >> 1;
    int kh = o / 3, kw = o % 3;
    int oc = mb * 16 + (l & 15);
    int kl0 = (l >> 4) * 8;
    bf16x8 v;
#pragma unroll
    for (int j = 0; j < 8; ++j) {
      int c = ch * 32 + kl0 + j;
      int ko = (c * 3 + kh) * 3 + kw;
      v[j] = (__bf16)w[ko * OCn + oc];
    }
    bs8 u; u.b = v;
    wpf[idx] = u.s;
    return;
  }
  int u = (bid >> 3) + (bid & 7) * 260;  // bijective: 2080 = 8 * 260
  int b = u / 130, hp = u - b * 130;
  size_t obase = ((size_t)b * HP + hp) * WP * Cc;
  s16x8 z = (s16x8){0, 0, 0, 0, 0, 0, 0, 0};
  if (hp == 0 || hp == HP - 1) {
    for (int ck = t; ck < WP * Cc / 8; ck += 256)
      *(s16x8*)(xp + obase + (size_t)ck * 8) = z;
    return;
  }
  int h = hp - 1;
  __shared__ float tile[Cc][Ww + 1];
  int wpx = t & 127, chalf = t >> 7;
#pragma unroll
  for (int k = 0; k < 32; ++k) {
    int c = chalf * 32 + k;
    tile[c][wpx] = __builtin_nontemporal_load(
        &x[(((size_t)b * Cc + c) * Hh + h) * Ww + wpx]);
  }
  __syncthreads();
#pragma unroll
  for (int k = 0; k < 4; ++k) {
    int idx = k * 256 + t;  // [0,1024): ww = idx>>3, cg = idx&7
    int ww = idx >> 3, cg = idx & 7;
    bf16x8 v;
#pragma unroll
    for (int j = 0; j < 8; ++j) v[j] = (__bf16)tile[cg * 8 + j][ww];
    bs8 uu; uu.b = v;
    *(s16x8*)(xp + obase + (size_t)(ww + 1) * Cc + cg * 8) = uu.s;
  }
  if (t < 16) {
    int wz = (t >> 3) ? (Ww + 1) : 0;  // wp = 0 or 129
    *(s16x8*)(xp + obase + (size_t)wz * Cc + (t & 7) * 8) = z;
  }
}

// ---------------- conv main kernel (round-3 structure, XCD-aligned swizzle) ----------------
__global__ __launch_bounds__(256) void conv_mfma_kernel(
    const unsigned short* __restrict__ xp, const s16x8* __restrict__ wpf,
    float* __restrict__ out) {
  __shared__ __align__(16) short xt[4 * SLOT_SHORTS];
  int tid = threadIdx.x;
  int bid = blockIdx.x;
  int wk = (bid >> 3) + (bid & 7) * 128;  // bijective: 1024 = 8 * 128; XCD k -> b in {2k,2k+1}
  int wt = wk & 1;
  int hb = (wk >> 1) & 31;
  int b = wk >> 6;
  int h0 = hb * HBLK;
  int wv = tid >> 6, lane = tid & 63;
  int l15 = lane & 15, l4 = lane >> 4;

  // async stage of image row h_img into slot (h_img+1)&3; linear LDS dest,
  // inverse-XOR-swizzled global source (chunk cg^(wl&7)), swizzle again on read.
  auto stage = [&](int h_img) {
    int slot = (h_img + 1) & 3;
    size_t rbase = (((size_t)b * HP + (h_img + 1)) * WP + wt * WT) * Cc;
    int cg = lane & 7, wo = lane >> 3;
    const unsigned short* src0 = xp + rbase + (size_t)wo * Cc + ((cg ^ wo) << 3);
    for (int i = wv; i < 9; i += 4) {
      const unsigned short* src = src0 + (size_t)i * 8 * Cc;
      short* dst = &xt[slot * SLOT_SHORTS + i * 512];
      __builtin_amdgcn_global_load_lds(
          (const __attribute__((address_space(1))) void*)src,
          (__attribute__((address_space(3))) void*)dst, 16, 0, 0);
    }
  };

  stage(h0 - 1);
  stage(h0);
  stage(h0 + 1);

  for (int i = 0; i < HBLK; ++i) {
    int h = h0 + i;
    __syncthreads();            // staged rows visible; prior readers done
    if (i < HBLK - 1) stage(h + 2);  // issue async prefetch before compute

    f32x4 acc[2][4];
#pragma unroll
    for (int mi = 0; mi < 2; ++mi)
#pragma unroll
      for (int ni = 0; ni < 4; ++ni)
        acc[mi][ni] = (f32x4){0.f, 0.f, 0.f, 0.f};

#pragma unroll
    for (int t = 0; t < NT; ++t) {
      int kh = t / 6, kw = (t >> 1) % 3, ch = t & 1;
      bf16x8 a0 = as_bf16x8(wpf[(t * 8 + wv * 2 + 0) * 64 + lane]);
      bf16x8 a1 = as_bf16x8(wpf[(t * 8 + wv * 2 + 1) * 64 + lane]);
      int slot = (h + kh) & 3;
      int cgr = ch * 4 + l4;  // reader's channel-chunk index
#pragma unroll
      for (int ni = 0; ni < 4; ++ni) {
        int wl2 = ni * 16 + l15 + kw;
        int caddr = slot * SLOT_SHORTS + wl2 * Cc + ((cgr ^ (wl2 & 7)) << 3);
        bf16x8 bfr = as_bf16x8(*(const s16x8*)&xt[caddr]);
        acc[0][ni] = __builtin_amdgcn_mfma_f32_16x16x32_bf16(a0, bfr, acc[0][ni], 0, 0, 0);
        acc[1][ni] = __builtin_amdgcn_mfma_f32_16x16x32_bf16(a1, bfr, acc[1][ni], 0, 0, 0);
      }
    }

    // D mapping: col(px)=lane&15, row(oc)=(lane>>4)*4 + r
#pragma unroll
    for (int mi = 0; mi < 2; ++mi)
#pragma unroll
      for (int ni = 0; ni < 4; ++ni) {
        int oc = wv * 32 + mi * 16 + l4 * 4;
        int w_img = wt * WT + ni * 16 + l15;
        float* po = out + (((size_t)(b * OCn + oc)) * Hh + h) * Ww + w_img;
#pragma unroll
        for (int r = 0; r < 4; ++r)
          __builtin_nontemporal_store(acc[mi][ni][r], po + (size_t)r * Hh * Ww);
      }
  }
}

extern "C" void kernel_launch(void* const* d_in, const int* in_sizes, int n_in,
                              void* d_out, int out_size, void* d_ws, size_t ws_size,
                              hipStream_t stream) {
  const float* x = (const float*)d_in[0];
  const float* w = (const float*)d_in[1];
  float* out = (float*)d_out;
  unsigned short* xp = (unsigned short*)d_ws;
  s16x8* wpf = (s16x8*)((char*)d_ws + XP_BYTES);
  prepass_kernel<<<PRE_BLOCKS + 36, 256, 0, stream>>>(x, w, xp, wpf);
  conv_mfma_kernel<<<1024, 256, 0, stream>>>(xp, (const s16x8*)wpf, out);
}